// Round 1
// baseline (455.487 us; speedup 1.0000x reference)
//
#include <hip/hip_runtime.h>

#define TSEQ 2048
#define DM   2048
#define NHEAD 16

typedef __bf16 bf16x8 __attribute__((ext_vector_type(8)));
typedef float  f32x4  __attribute__((ext_vector_type(4)));
typedef unsigned short ushort8v __attribute__((ext_vector_type(8)));
typedef const __attribute__((address_space(1))) void* gas_cvp;
typedef __attribute__((address_space(3))) void* las_vp;

__device__ __forceinline__ unsigned short f2bf(float f) {
  unsigned int u = __builtin_bit_cast(unsigned int, f);
  u += 0x7FFFu + ((u >> 16) & 1u);
  return (unsigned short)(u >> 16);
}

// ---------------- fp32 -> bf16 conversion (8 elems/thread) ----------------
__global__ __launch_bounds__(256) void cvt_bf16(const float* __restrict__ in,
                                                unsigned short* __restrict__ out,
                                                int n8) {
  int i = blockIdx.x * 256 + threadIdx.x;
  if (i >= n8) return;
  const float4* p = (const float4*)in + (size_t)i * 2;
  float4 a = p[0], b = p[1];
  ushort8v o;
  o[0] = f2bf(a.x); o[1] = f2bf(a.y); o[2] = f2bf(a.z); o[3] = f2bf(a.w);
  o[4] = f2bf(b.x); o[5] = f2bf(b.y); o[6] = f2bf(b.z); o[7] = f2bf(b.w);
  *((ushort8v*)out + i) = o;
}

// ---------------- GEMM: C[M][N] = A[M][K] * B[N][K]^T (both K-major bf16) --
// 128x128 tile, BK=64, 4 waves (2x2), 16x16x32 bf16 MFMA, global_load_lds.
__global__ __launch_bounds__(256) void gemm_bt(const unsigned short* __restrict__ A,
                                               const unsigned short* __restrict__ B,
                                               float* __restrict__ C,
                                               int M, int N, int K) {
  __shared__ unsigned short As[128 * 64];
  __shared__ unsigned short Bs[128 * 64];
  int tid = threadIdx.x;
  int w = tid >> 6, lane = tid & 63;
  int l15 = lane & 15, l4 = lane >> 4;
  int wm = w >> 1, wn = w & 1;
  int tileN = blockIdx.x * 128, tileM = blockIdx.y * 128;

  f32x4 acc[4][4] = {};

  int srow  = lane >> 3;        // 0..7  (row within 8-row chunk)
  int scolb = (lane & 7) * 16;  // byte col within 128B row
  const char* Ab = (const char*)(A + (size_t)tileM * K);
  const char* Bb = (const char*)(B + (size_t)tileN * K);
  size_t pitch = (size_t)K * 2;

  for (int k0 = 0; k0 < K; k0 += 64) {
    // ---- stage A,B tiles (each wave: 4 chunks of 1KB per tile) ----
    #pragma unroll
    for (int c = 0; c < 4; ++c) {
      int ch = w * 4 + c;              // 0..15, wave-uniform
      int row = ch * 8 + srow;         // 0..127
      const char* ga = Ab + (size_t)row * pitch + (size_t)k0 * 2 + scolb;
      const char* gb = Bb + (size_t)row * pitch + (size_t)k0 * 2 + scolb;
      __builtin_amdgcn_global_load_lds((gas_cvp)ga, (las_vp)((char*)As + ch * 1024), 16, 0, 0);
      __builtin_amdgcn_global_load_lds((gas_cvp)gb, (las_vp)((char*)Bs + ch * 1024), 16, 0, 0);
    }
    __syncthreads();
    // ---- compute: 2 x (K=32) MFMA sub-steps ----
    #pragma unroll
    for (int kk = 0; kk < 2; ++kk) {
      int koff = kk * 32 + l4 * 8;
      bf16x8 af[4], bfr[4];
      #pragma unroll
      for (int m = 0; m < 4; ++m)
        af[m] = *(const bf16x8*)&As[(wm * 64 + m * 16 + l15) * 64 + koff];
      #pragma unroll
      for (int n = 0; n < 4; ++n)
        bfr[n] = *(const bf16x8*)&Bs[(wn * 64 + n * 16 + l15) * 64 + koff];
      #pragma unroll
      for (int m = 0; m < 4; ++m)
        #pragma unroll
        for (int n = 0; n < 4; ++n)
          acc[m][n] = __builtin_amdgcn_mfma_f32_16x16x32_bf16(af[m], bfr[n], acc[m][n], 0, 0, 0);
    }
    __syncthreads();
  }
  // ---- epilogue: fp32 C write ----
  #pragma unroll
  for (int m = 0; m < 4; ++m) {
    int r0 = tileM + wm * 64 + m * 16 + l4 * 4;
    #pragma unroll
    for (int n = 0; n < 4; ++n) {
      int c0 = tileN + wn * 64 + n * 16 + l15;
      #pragma unroll
      for (int j = 0; j < 4; ++j)
        C[(size_t)(r0 + j) * N + c0] = acc[m][n][j];
    }
  }
}

// ---------------- v-mix + RMSNorm + RoPE (one wave per (t,h)) -------------
__global__ __launch_bounds__(256) void qkv_post(const float* __restrict__ qkv,
                                                const float* __restrict__ vi,
                                                const float* __restrict__ lam,
                                                unsigned short* __restrict__ qb,
                                                unsigned short* __restrict__ kb,
                                                unsigned short* __restrict__ vb) {
  int wid = blockIdx.x * 4 + (threadIdx.x >> 6);
  int lane = threadIdx.x & 63;
  int t = wid >> 4, h = wid & 15;
  const float* base = qkv + (size_t)t * (3 * DM) + h * 128;
  float l0 = lam[0], l1 = lam[1];

  // rope: inv_freq = 10000^(-2*lane/128) = 2^(-lane * log2(10000)/64)
  float invf = exp2f((float)lane * -0.20762050593046014f);
  float ang = (float)t * invf;
  float sn, cs;
  sincosf(ang, &sn, &cs);

  size_t ob = (size_t)t * DM + h * 128;
  // ---- q ----
  {
    float a = base[lane], b = base[lane + 64];
    float ss = a * a + b * b;
    #pragma unroll
    for (int m = 1; m < 64; m <<= 1) ss += __shfl_xor(ss, m, 64);
    float sc = rsqrtf(ss * (1.0f / 128.0f) + 1.1920929e-07f);
    a *= sc; b *= sc;
    qb[ob + lane]      = f2bf(a * cs + b * sn);
    qb[ob + 64 + lane] = f2bf(b * cs - a * sn);
  }
  // ---- k ----
  {
    float a = base[2048 + lane], b = base[2048 + 64 + lane];
    float ss = a * a + b * b;
    #pragma unroll
    for (int m = 1; m < 64; m <<= 1) ss += __shfl_xor(ss, m, 64);
    float sc = rsqrtf(ss * (1.0f / 128.0f) + 1.1920929e-07f);
    a *= sc; b *= sc;
    kb[ob + lane]      = f2bf(a * cs + b * sn);
    kb[ob + 64 + lane] = f2bf(b * cs - a * sn);
  }
  // ---- v ----
  {
    const float* vib = vi + (size_t)t * DM + h * 128;
    vb[ob + lane]      = f2bf(l0 * base[4096 + lane]      + l1 * vib[lane]);
    vb[ob + 64 + lane] = f2bf(l0 * base[4096 + 64 + lane] + l1 * vib[lane + 64]);
  }
}

// ---------------- V transpose: vb[t][h*128+d] -> vbT[h][d][t] -------------
__global__ __launch_bounds__(256) void transpose_v(const unsigned short* __restrict__ vb,
                                                   unsigned short* __restrict__ vbT) {
  __shared__ __align__(16) unsigned short tile[64][68];
  int t0 = blockIdx.x * 64, d0 = blockIdx.y * 64, h = blockIdx.z;
  int tid = threadIdx.x;
  int li = tid >> 4;         // 0..15
  int lj = (tid & 15) * 4;   // 0..60
  #pragma unroll
  for (int p = 0; p < 4; ++p) {
    int i = p * 16 + li;
    ushort4 v = *(const ushort4*)(vb + (size_t)(t0 + i) * DM + h * 128 + d0 + lj);
    tile[i][lj] = v.x; tile[i][lj + 1] = v.y; tile[i][lj + 2] = v.z; tile[i][lj + 3] = v.w;
  }
  __syncthreads();
  #pragma unroll
  for (int p = 0; p < 4; ++p) {
    int j = p * 16 + li;
    ushort4 wv;
    wv.x = tile[lj][j]; wv.y = tile[lj + 1][j]; wv.z = tile[lj + 2][j]; wv.w = tile[lj + 3][j];
    *(ushort4*)(vbT + (size_t)h * 128 * TSEQ + (size_t)(d0 + j) * TSEQ + t0 + lj) = wv;
  }
}

// ---------------- causal flash attention -----------------------------------
// grid (T/64, H); 4 waves; wave w owns q rows qblk*64+w*16 .. +15.
__global__ __launch_bounds__(256) void attn_fwd(const unsigned short* __restrict__ qb,
                                                const unsigned short* __restrict__ kb,
                                                const unsigned short* __restrict__ vbT,
                                                unsigned short* __restrict__ yb) {
  __shared__ __align__(16) unsigned short p_lds[4][16][80];
  int qblk = blockIdx.x, h = blockIdx.y;
  int tid = threadIdx.x, w = tid >> 6, lane = tid & 63;
  int l15 = lane & 15, l4 = lane >> 4;
  int qr0 = qblk * 64 + w * 16;

  // Q fragments (A-operand), row = qr0 + l15, k = kk*32 + l4*8
  const unsigned short* qrow = qb + (size_t)(qr0 + l15) * DM + h * 128 + l4 * 8;
  bf16x8 a_q[4];
  #pragma unroll
  for (int kk = 0; kk < 4; ++kk) a_q[kk] = *(const bf16x8*)(qrow + kk * 32);

  f32x4 acc_o[8] = {};
  float mrow[4] = {-1e30f, -1e30f, -1e30f, -1e30f};
  float lrow[4] = {0.f, 0.f, 0.f, 0.f};
  const float scale = 0.08838834764831845f; // 1/sqrt(128)
  const unsigned short* vhead = vbT + (size_t)h * 128 * TSEQ;

  int nkv = qblk + 1;
  for (int kvb = 0; kvb < nkv; ++kvb) {
    int kv0 = kvb * 64;
    // ---- S = Q K^T (16 q-rows x 64 kv) ----
    f32x4 acc_s[4] = {};
    #pragma unroll
    for (int j = 0; j < 4; ++j) {
      const unsigned short* krow = kb + (size_t)(kv0 + j * 16 + l15) * DM + h * 128 + l4 * 8;
      #pragma unroll
      for (int kk = 0; kk < 4; ++kk) {
        bf16x8 bk = *(const bf16x8*)(krow + kk * 32);
        acc_s[j] = __builtin_amdgcn_mfma_f32_16x16x32_bf16(a_q[kk], bk, acc_s[j], 0, 0, 0);
      }
    }
    // ---- scale + causal mask + online softmax ----
    bool diag = (kvb == qblk);
    float sv[4][4];
    float pmax[4] = {-1e30f, -1e30f, -1e30f, -1e30f};
    #pragma unroll
    for (int j = 0; j < 4; ++j)
      #pragma unroll
      for (int r = 0; r < 4; ++r) {
        float s = acc_s[j][r] * scale;
        if (diag && (kv0 + j * 16 + l15) > (qr0 + l4 * 4 + r)) s = -1e30f;
        sv[j][r] = s;
        pmax[r] = fmaxf(pmax[r], s);
      }
    #pragma unroll
    for (int m = 1; m < 16; m <<= 1)
      #pragma unroll
      for (int r = 0; r < 4; ++r) pmax[r] = fmaxf(pmax[r], __shfl_xor(pmax[r], m, 64));
    float f[4], psum[4] = {0, 0, 0, 0};
    #pragma unroll
    for (int r = 0; r < 4; ++r) {
      float mn = fmaxf(mrow[r], pmax[r]);
      f[r] = __expf(mrow[r] - mn);
      mrow[r] = mn;
    }
    #pragma unroll
    for (int j = 0; j < 4; ++j)
      #pragma unroll
      for (int r = 0; r < 4; ++r) {
        float p = __expf(sv[j][r] - mrow[r]);
        psum[r] += p;
        p_lds[w][l4 * 4 + r][j * 16 + l15] = f2bf(p);
      }
    #pragma unroll
    for (int m = 1; m < 16; m <<= 1)
      #pragma unroll
      for (int r = 0; r < 4; ++r) psum[r] += __shfl_xor(psum[r], m, 64);
    #pragma unroll
    for (int r = 0; r < 4; ++r) lrow[r] = lrow[r] * f[r] + psum[r];
    #pragma unroll
    for (int n = 0; n < 8; ++n)
      #pragma unroll
      for (int r = 0; r < 4; ++r) acc_o[n][r] *= f[r];
    // ensure wave-local LDS writes complete before fragment reads
    asm volatile("s_waitcnt lgkmcnt(0)" ::: "memory");
    __builtin_amdgcn_sched_barrier(0);
    // ---- O += P V ----
    #pragma unroll
    for (int kk = 0; kk < 2; ++kk) {
      bf16x8 a_p = *(const bf16x8*)&p_lds[w][l15][kk * 32 + l4 * 8];
      #pragma unroll
      for (int n = 0; n < 8; ++n) {
        const unsigned short* vrow = vhead + (size_t)(n * 16 + l15) * TSEQ + kv0 + kk * 32 + l4 * 8;
        bf16x8 bv = *(const bf16x8*)vrow;
        acc_o[n] = __builtin_amdgcn_mfma_f32_16x16x32_bf16(a_p, bv, acc_o[n], 0, 0, 0);
      }
    }
  }
  // ---- epilogue: O / l -> bf16 y[t][h*128+d] ----
  #pragma unroll
  for (int n = 0; n < 8; ++n)
    #pragma unroll
    for (int r = 0; r < 4; ++r) {
      float o = acc_o[n][r] / lrow[r];
      yb[(size_t)(qr0 + l4 * 4 + r) * DM + h * 128 + n * 16 + l15] = f2bf(o);
    }
}

// ---------------------------------------------------------------------------
extern "C" void kernel_launch(void* const* d_in, const int* in_sizes, int n_in,
                              void* d_out, int out_size, void* d_ws, size_t ws_size,
                              hipStream_t stream) {
  const float* x   = (const float*)d_in[0];
  const float* vi  = (const float*)d_in[1];
  const float* wq  = (const float*)d_in[2];
  const float* wk  = (const float*)d_in[3];
  const float* wv  = (const float*)d_in[4];
  const float* wp  = (const float*)d_in[5];
  const float* lam = (const float*)d_in[6];

  const size_t MB = 1024 * 1024;
  const int NEL = DM * TSEQ;       // 4M elements per [2048,2048] tensor
  const int N8  = NEL / 8;         // 524288
  char* ws = (char*)d_ws;
  unsigned short* xb    = (unsigned short*)(ws);            //  8 MB
  unsigned short* wqkvb = (unsigned short*)(ws + 8  * MB);   // 24 MB (wq|wk|wv rows)
  unsigned short* wpb   = (unsigned short*)(ws + 32 * MB);   //  8 MB
  float*          qkv32 = (float*)(ws + 40 * MB);            // 48 MB [T][6144]
  unsigned short* qb2   = (unsigned short*)(ws + 88 * MB);   //  8 MB
  unsigned short* kb2   = (unsigned short*)(ws + 96 * MB);   //  8 MB
  unsigned short* vb    = (unsigned short*)(ws + 104 * MB);  //  8 MB
  unsigned short* vbT   = (unsigned short*)(ws + 112 * MB);  //  8 MB [h][d][t]
  unsigned short* yb    = (unsigned short*)(ws + 120 * MB);  //  8 MB

  // 1) bf16 conversions (wq,wk,wv packed contiguously -> one QKV GEMM)
  cvt_bf16<<<N8 / 256, 256, 0, stream>>>(x,  xb, N8);
  cvt_bf16<<<N8 / 256, 256, 0, stream>>>(wq, wqkvb,            N8);
  cvt_bf16<<<N8 / 256, 256, 0, stream>>>(wk, wqkvb + (size_t)NEL,     N8);
  cvt_bf16<<<N8 / 256, 256, 0, stream>>>(wv, wqkvb + (size_t)2 * NEL, N8);
  cvt_bf16<<<N8 / 256, 256, 0, stream>>>(wp, wpb, N8);

  // 2) QKV projection: [2048,2048] x [6144,2048]^T -> fp32 [2048,6144]
  gemm_bt<<<dim3(6144 / 128, TSEQ / 128), 256, 0, stream>>>(xb, wqkvb, qkv32, TSEQ, 3 * DM, DM);

  // 3) v-mix + RMSNorm + RoPE -> bf16 q,k,v
  qkv_post<<<(TSEQ * NHEAD) / 4, 256, 0, stream>>>(qkv32, vi, lam, qb2, kb2, vb);

  // 4) V transpose for PV B-operand
  transpose_v<<<dim3(TSEQ / 64, 2, NHEAD), 256, 0, stream>>>(vb, vbT);

  // 5) causal flash attention -> bf16 y [t][h*128+d]
  attn_fwd<<<dim3(TSEQ / 64, NHEAD), 256, 0, stream>>>(qb2, kb2, vbT, yb);

  // 6) output projection -> fp32 d_out
  gemm_bt<<<dim3(DM / 128, TSEQ / 128), 256, 0, stream>>>(yb, wpb, (float*)d_out, TSEQ, DM, DM);
}

// Round 2
// 267.317 us; speedup vs baseline: 1.7039x; 1.7039x over previous
//
#include <hip/hip_runtime.h>

#define TSEQ 2048
#define DM   2048
#define NHEAD 16

typedef __bf16 bf16x8 __attribute__((ext_vector_type(8)));
typedef float  f32x4  __attribute__((ext_vector_type(4)));
typedef unsigned short ushort8v __attribute__((ext_vector_type(8)));
typedef const __attribute__((address_space(1))) void* gas_cvp;
typedef __attribute__((address_space(3))) void* las_vp;

__device__ __forceinline__ unsigned short f2bf(float f) {
  unsigned int u = __builtin_bit_cast(unsigned int, f);
  u += 0x7FFFu + ((u >> 16) & 1u);
  return (unsigned short)(u >> 16);
}

// ---------------- fp32 -> bf16 conversion (8 elems/thread) ----------------
__global__ __launch_bounds__(256) void cvt_bf16(const float* __restrict__ in,
                                                unsigned short* __restrict__ out,
                                                int n8) {
  int i = blockIdx.x * 256 + threadIdx.x;
  if (i >= n8) return;
  const float4* p = (const float4*)in + (size_t)i * 2;
  float4 a = p[0], b = p[1];
  ushort8v o;
  o[0] = f2bf(a.x); o[1] = f2bf(a.y); o[2] = f2bf(a.z); o[3] = f2bf(a.w);
  o[4] = f2bf(b.x); o[5] = f2bf(b.y); o[6] = f2bf(b.z); o[7] = f2bf(b.w);
  *((ushort8v*)out + i) = o;
}

// ---------------- GEMM: C[M][N] = A[M][K] * B[N][K]^T (both K-major bf16) --
__global__ __launch_bounds__(256) void gemm_bt(const unsigned short* __restrict__ A,
                                               const unsigned short* __restrict__ B,
                                               float* __restrict__ C,
                                               int M, int N, int K) {
  __shared__ unsigned short As[128 * 64];
  __shared__ unsigned short Bs[128 * 64];
  int tid = threadIdx.x;
  int w = tid >> 6, lane = tid & 63;
  int l15 = lane & 15, l4 = lane >> 4;
  int wm = w >> 1, wn = w & 1;
  int tileN = blockIdx.x * 128, tileM = blockIdx.y * 128;

  f32x4 acc[4][4] = {};

  int srow  = lane >> 3;
  int scolb = (lane & 7) * 16;
  const char* Ab = (const char*)(A + (size_t)tileM * K);
  const char* Bb = (const char*)(B + (size_t)tileN * K);
  size_t pitch = (size_t)K * 2;

  for (int k0 = 0; k0 < K; k0 += 64) {
    #pragma unroll
    for (int c = 0; c < 4; ++c) {
      int ch = w * 4 + c;
      int row = ch * 8 + srow;
      const char* ga = Ab + (size_t)row * pitch + (size_t)k0 * 2 + scolb;
      const char* gb = Bb + (size_t)row * pitch + (size_t)k0 * 2 + scolb;
      __builtin_amdgcn_global_load_lds((gas_cvp)ga, (las_vp)((char*)As + ch * 1024), 16, 0, 0);
      __builtin_amdgcn_global_load_lds((gas_cvp)gb, (las_vp)((char*)Bs + ch * 1024), 16, 0, 0);
    }
    __syncthreads();
    #pragma unroll
    for (int kk = 0; kk < 2; ++kk) {
      int koff = kk * 32 + l4 * 8;
      bf16x8 af[4], bfr[4];
      #pragma unroll
      for (int m = 0; m < 4; ++m)
        af[m] = *(const bf16x8*)&As[(wm * 64 + m * 16 + l15) * 64 + koff];
      #pragma unroll
      for (int n = 0; n < 4; ++n)
        bfr[n] = *(const bf16x8*)&Bs[(wn * 64 + n * 16 + l15) * 64 + koff];
      #pragma unroll
      for (int m = 0; m < 4; ++m)
        #pragma unroll
        for (int n = 0; n < 4; ++n)
          acc[m][n] = __builtin_amdgcn_mfma_f32_16x16x32_bf16(af[m], bfr[n], acc[m][n], 0, 0, 0);
    }
    __syncthreads();
  }
  #pragma unroll
  for (int m = 0; m < 4; ++m) {
    int r0 = tileM + wm * 64 + m * 16 + l4 * 4;
    #pragma unroll
    for (int n = 0; n < 4; ++n) {
      int c0 = tileN + wn * 64 + n * 16 + l15;
      #pragma unroll
      for (int j = 0; j < 4; ++j)
        C[(size_t)(r0 + j) * N + c0] = acc[m][n][j];
    }
  }
}

// ---------------- v-mix + RMSNorm + RoPE (one wave per (t,h)) -------------
__global__ __launch_bounds__(256) void qkv_post(const float* __restrict__ qkv,
                                                const float* __restrict__ vi,
                                                const float* __restrict__ lam,
                                                unsigned short* __restrict__ qb,
                                                unsigned short* __restrict__ kb,
                                                unsigned short* __restrict__ vb) {
  int wid = blockIdx.x * 4 + (threadIdx.x >> 6);
  int lane = threadIdx.x & 63;
  int t = wid >> 4, h = wid & 15;
  const float* base = qkv + (size_t)t * (3 * DM) + h * 128;
  float l0 = lam[0], l1 = lam[1];

  float invf = exp2f((float)lane * -0.20762050593046014f);
  float ang = (float)t * invf;
  float sn, cs;
  sincosf(ang, &sn, &cs);

  size_t ob = (size_t)t * DM + h * 128;
  {
    float a = base[lane], b = base[lane + 64];
    float ss = a * a + b * b;
    #pragma unroll
    for (int m = 1; m < 64; m <<= 1) ss += __shfl_xor(ss, m, 64);
    float sc = rsqrtf(ss * (1.0f / 128.0f) + 1.1920929e-07f);
    a *= sc; b *= sc;
    qb[ob + lane]      = f2bf(a * cs + b * sn);
    qb[ob + 64 + lane] = f2bf(b * cs - a * sn);
  }
  {
    float a = base[2048 + lane], b = base[2048 + 64 + lane];
    float ss = a * a + b * b;
    #pragma unroll
    for (int m = 1; m < 64; m <<= 1) ss += __shfl_xor(ss, m, 64);
    float sc = rsqrtf(ss * (1.0f / 128.0f) + 1.1920929e-07f);
    a *= sc; b *= sc;
    kb[ob + lane]      = f2bf(a * cs + b * sn);
    kb[ob + 64 + lane] = f2bf(b * cs - a * sn);
  }
  {
    const float* vib = vi + (size_t)t * DM + h * 128;
    vb[ob + lane]      = f2bf(l0 * base[4096 + lane]      + l1 * vib[lane]);
    vb[ob + 64 + lane] = f2bf(l0 * base[4096 + 64 + lane] + l1 * vib[lane + 64]);
  }
}

// ---------------- V transpose: vb[t][h*128+d] -> vbT[h][d][t] -------------
__global__ __launch_bounds__(256) void transpose_v(const unsigned short* __restrict__ vb,
                                                   unsigned short* __restrict__ vbT) {
  __shared__ __align__(16) unsigned short tile[64][68];
  int t0 = blockIdx.x * 64, d0 = blockIdx.y * 64, h = blockIdx.z;
  int tid = threadIdx.x;
  int li = tid >> 4;
  int lj = (tid & 15) * 4;
  #pragma unroll
  for (int p = 0; p < 4; ++p) {
    int i = p * 16 + li;
    ushort4 v = *(const ushort4*)(vb + (size_t)(t0 + i) * DM + h * 128 + d0 + lj);
    tile[i][lj] = v.x; tile[i][lj + 1] = v.y; tile[i][lj + 2] = v.z; tile[i][lj + 3] = v.w;
  }
  __syncthreads();
  #pragma unroll
  for (int p = 0; p < 4; ++p) {
    int j = p * 16 + li;
    ushort4 wv;
    wv.x = tile[lj][j]; wv.y = tile[lj + 1][j]; wv.z = tile[lj + 2][j]; wv.w = tile[lj + 3][j];
    *(ushort4*)(vbT + (size_t)h * 128 * TSEQ + (size_t)(d0 + j) * TSEQ + t0 + lj) = wv;
  }
}

// ---------------- causal flash attention -----------------------------------
// grid (T/64, H); 4 waves; wave w owns q rows qblk*64+w*16..+15.
// K (64x128) and V^T (128x64) tiles staged in LDS (double-buffered,
// global_load_lds w=16, XOR-swizzled via pre-swizzled global source).
__global__ __launch_bounds__(256) void attn_fwd(const unsigned short* __restrict__ qb,
                                                const unsigned short* __restrict__ kb,
                                                const unsigned short* __restrict__ vbT,
                                                unsigned short* __restrict__ yb) {
  __shared__ __align__(16) char Ks[2][16384];   // 64 rows x 256B (k rows, swizzled)
  __shared__ __align__(16) char Vs[2][16384];   // 128 rows x 128B (d rows, swizzled)
  __shared__ __align__(16) unsigned short p_lds[4][16][80];

  int qblk = (int)gridDim.x - 1 - (int)blockIdx.x;   // heavy blocks first
  int h = blockIdx.y;
  int tid = threadIdx.x, w = tid >> 6, lane = tid & 63;
  int l15 = lane & 15, l4 = lane >> 4;
  int qr0 = qblk * 64 + w * 16;
  int xorK = (l15 & 7) << 4;

  // Q fragments (A-operand): row = qr0 + l15, k = kk*32 + l4*8
  const unsigned short* qrow = qb + (size_t)(qr0 + l15) * DM + h * 128 + l4 * 8;
  bf16x8 a_q[4];
  #pragma unroll
  for (int kk = 0; kk < 4; ++kk) a_q[kk] = *(const bf16x8*)(qrow + kk * 32);

  const char* kbase = (const char*)kb + (size_t)h * 256;            // + t*4096
  const char* vbase = (const char*)vbT + (size_t)h * 128 * TSEQ * 2; // + d*4096 + t*2

  f32x4 acc_o[8] = {};
  float mrow[4] = {-1e30f, -1e30f, -1e30f, -1e30f};
  float lrow[4] = {0.f, 0.f, 0.f, 0.f};
  const float scale = 0.08838834764831845f; // 1/sqrt(128)

  int nkv = qblk + 1;

  // ---- prologue: stage kv-block 0 into buffer 0 ----
  {
    #pragma unroll
    for (int it = 0; it < 4; ++it) {
      int L = (it * 256 + tid) * 16;
      int row = L >> 8, b = L & 255;
      const char* src = kbase + (size_t)row * 4096 + (b ^ ((row & 7) << 4));
      __builtin_amdgcn_global_load_lds((gas_cvp)src, (las_vp)(&Ks[0][0] + L), 16, 0, 0);
    }
    #pragma unroll
    for (int it = 0; it < 4; ++it) {
      int L = (it * 256 + tid) * 16;
      int row = L >> 7, b = L & 127;
      const char* src = vbase + (size_t)row * (TSEQ * 2) + (b ^ ((row & 7) << 4));
      __builtin_amdgcn_global_load_lds((gas_cvp)src, (las_vp)(&Vs[0][0] + L), 16, 0, 0);
    }
  }
  __syncthreads();

  int buf = 0;
  for (int kvb = 0; kvb < nkv; ++kvb) {
    int kv0 = kvb * 64;
    // ---- issue next-tile stage (overlaps with compute below) ----
    if (kvb + 1 < nkv) {
      int kv1 = (kvb + 1) * 64;
      const char* kb1 = kbase + (size_t)kv1 * 4096;
      const char* vb1 = vbase + (size_t)kv1 * 2;
      char* kd = &Ks[buf ^ 1][0];
      char* vd = &Vs[buf ^ 1][0];
      #pragma unroll
      for (int it = 0; it < 4; ++it) {
        int L = (it * 256 + tid) * 16;
        int row = L >> 8, b = L & 255;
        const char* src = kb1 + (size_t)row * 4096 + (b ^ ((row & 7) << 4));
        __builtin_amdgcn_global_load_lds((gas_cvp)src, (las_vp)(kd + L), 16, 0, 0);
      }
      #pragma unroll
      for (int it = 0; it < 4; ++it) {
        int L = (it * 256 + tid) * 16;
        int row = L >> 7, b = L & 127;
        const char* src = vb1 + (size_t)row * (TSEQ * 2) + (b ^ ((row & 7) << 4));
        __builtin_amdgcn_global_load_lds((gas_cvp)src, (las_vp)(vd + L), 16, 0, 0);
      }
    }

    const char* ksb = &Ks[buf][0];
    const char* vsb = &Vs[buf][0];

    // ---- S = Q K^T (16 q-rows x 64 kv), K from LDS ----
    f32x4 acc_s[4] = {};
    __builtin_amdgcn_s_setprio(1);
    #pragma unroll
    for (int j = 0; j < 4; ++j) {
      const char* kr = ksb + (j * 16 + l15) * 256;
      #pragma unroll
      for (int kk = 0; kk < 4; ++kk) {
        bf16x8 bk = *(const bf16x8*)(kr + ((l4 * 16 + kk * 64) ^ xorK));
        acc_s[j] = __builtin_amdgcn_mfma_f32_16x16x32_bf16(a_q[kk], bk, acc_s[j], 0, 0, 0);
      }
    }
    __builtin_amdgcn_s_setprio(0);

    // ---- scale + causal mask + online softmax ----
    bool diag = (kvb == qblk);
    float sv[4][4];
    float pmax[4] = {-1e30f, -1e30f, -1e30f, -1e30f};
    #pragma unroll
    for (int j = 0; j < 4; ++j)
      #pragma unroll
      for (int r = 0; r < 4; ++r) {
        float s = acc_s[j][r] * scale;
        if (diag && (kv0 + j * 16 + l15) > (qr0 + l4 * 4 + r)) s = -1e30f;
        sv[j][r] = s;
        pmax[r] = fmaxf(pmax[r], s);
      }
    #pragma unroll
    for (int m = 1; m < 16; m <<= 1)
      #pragma unroll
      for (int r = 0; r < 4; ++r) pmax[r] = fmaxf(pmax[r], __shfl_xor(pmax[r], m, 64));
    float f[4], psum[4] = {0, 0, 0, 0};
    #pragma unroll
    for (int r = 0; r < 4; ++r) {
      float mn = fmaxf(mrow[r], pmax[r]);
      f[r] = __expf(mrow[r] - mn);
      mrow[r] = mn;
    }
    #pragma unroll
    for (int j = 0; j < 4; ++j)
      #pragma unroll
      for (int r = 0; r < 4; ++r) {
        float p = __expf(sv[j][r] - mrow[r]);
        psum[r] += p;
        p_lds[w][l4 * 4 + r][j * 16 + l15] = f2bf(p);
      }
    #pragma unroll
    for (int m = 1; m < 16; m <<= 1)
      #pragma unroll
      for (int r = 0; r < 4; ++r) psum[r] += __shfl_xor(psum[r], m, 64);
    #pragma unroll
    for (int r = 0; r < 4; ++r) lrow[r] = lrow[r] * f[r] + psum[r];
    #pragma unroll
    for (int n = 0; n < 8; ++n)
      #pragma unroll
      for (int r = 0; r < 4; ++r) acc_o[n][r] *= f[r];
    // wave-local LDS writes must complete before fragment reads
    asm volatile("s_waitcnt lgkmcnt(0)" ::: "memory");
    __builtin_amdgcn_sched_barrier(0);

    // ---- O += P V, V^T from LDS ----
    __builtin_amdgcn_s_setprio(1);
    #pragma unroll
    for (int kk = 0; kk < 2; ++kk) {
      bf16x8 a_p = *(const bf16x8*)&p_lds[w][l15][kk * 32 + l4 * 8];
      #pragma unroll
      for (int n = 0; n < 8; ++n) {
        const char* vr = vsb + (n * 16 + l15) * 128;
        bf16x8 bv = *(const bf16x8*)(vr + ((kk * 64 + l4 * 16) ^ xorK));
        acc_o[n] = __builtin_amdgcn_mfma_f32_16x16x32_bf16(a_p, bv, acc_o[n], 0, 0, 0);
      }
    }
    __builtin_amdgcn_s_setprio(0);

    __syncthreads();   // drains vmcnt(0) (next stage) + all waves done with buf
    buf ^= 1;
  }

  // ---- epilogue: O / l -> bf16 y[t][h*128+d] ----
  #pragma unroll
  for (int n = 0; n < 8; ++n)
    #pragma unroll
    for (int r = 0; r < 4; ++r) {
      float o = acc_o[n][r] / lrow[r];
      yb[(size_t)(qr0 + l4 * 4 + r) * DM + h * 128 + n * 16 + l15] = f2bf(o);
    }
}

// ---------------------------------------------------------------------------
extern "C" void kernel_launch(void* const* d_in, const int* in_sizes, int n_in,
                              void* d_out, int out_size, void* d_ws, size_t ws_size,
                              hipStream_t stream) {
  const float* x   = (const float*)d_in[0];
  const float* vi  = (const float*)d_in[1];
  const float* wq  = (const float*)d_in[2];
  const float* wk  = (const float*)d_in[3];
  const float* wv  = (const float*)d_in[4];
  const float* wp  = (const float*)d_in[5];
  const float* lam = (const float*)d_in[6];

  const size_t MB = 1024 * 1024;
  const int NEL = DM * TSEQ;
  const int N8  = NEL / 8;
  char* ws = (char*)d_ws;
  unsigned short* xb    = (unsigned short*)(ws);
  unsigned short* wqkvb = (unsigned short*)(ws + 8  * MB);
  unsigned short* wpb   = (unsigned short*)(ws + 32 * MB);
  float*          qkv32 = (float*)(ws + 40 * MB);
  unsigned short* qb2   = (unsigned short*)(ws + 88 * MB);
  unsigned short* kb2   = (unsigned short*)(ws + 96 * MB);
  unsigned short* vb    = (unsigned short*)(ws + 104 * MB);
  unsigned short* vbT   = (unsigned short*)(ws + 112 * MB);
  unsigned short* yb    = (unsigned short*)(ws + 120 * MB);

  cvt_bf16<<<N8 / 256, 256, 0, stream>>>(x,  xb, N8);
  cvt_bf16<<<N8 / 256, 256, 0, stream>>>(wq, wqkvb,                  N8);
  cvt_bf16<<<N8 / 256, 256, 0, stream>>>(wk, wqkvb + (size_t)NEL,     N8);
  cvt_bf16<<<N8 / 256, 256, 0, stream>>>(wv, wqkvb + (size_t)2 * NEL, N8);
  cvt_bf16<<<N8 / 256, 256, 0, stream>>>(wp, wpb, N8);

  gemm_bt<<<dim3(6144 / 128, TSEQ / 128), 256, 0, stream>>>(xb, wqkvb, qkv32, TSEQ, 3 * DM, DM);

  qkv_post<<<(TSEQ * NHEAD) / 4, 256, 0, stream>>>(qkv32, vi, lam, qb2, kb2, vb);

  transpose_v<<<dim3(TSEQ / 64, 2, NHEAD), 256, 0, stream>>>(vb, vbT);

  attn_fwd<<<dim3(TSEQ / 64, NHEAD), 256, 0, stream>>>(qb2, kb2, vbT, yb);

  gemm_bt<<<dim3(DM / 128, TSEQ / 128), 256, 0, stream>>>(yb, wpb, (float*)d_out, TSEQ, DM, DM);
}

// Round 3
// 222.977 us; speedup vs baseline: 2.0428x; 1.1989x over previous
//
#include <hip/hip_runtime.h>

#define TSEQ 2048
#define DM   2048
#define NHEAD 16

typedef __bf16 bf16x8 __attribute__((ext_vector_type(8)));
typedef float  f32x4  __attribute__((ext_vector_type(4)));
typedef unsigned short ushort8v __attribute__((ext_vector_type(8)));
typedef const __attribute__((address_space(1))) void* gas_cvp;
typedef __attribute__((address_space(3))) void* las_vp;

__device__ __forceinline__ unsigned short f2bf(float f) {
  unsigned int u = __builtin_bit_cast(unsigned int, f);
  u += 0x7FFFu + ((u >> 16) & 1u);
  return (unsigned short)(u >> 16);
}

// ---------------- fp32 -> bf16 conversion (8 elems/thread) ----------------
__global__ __launch_bounds__(256) void cvt_bf16(const float* __restrict__ in,
                                                unsigned short* __restrict__ out,
                                                int n8) {
  int i = blockIdx.x * 256 + threadIdx.x;
  if (i >= n8) return;
  const float4* p = (const float4*)in + (size_t)i * 2;
  float4 a = p[0], b = p[1];
  ushort8v o;
  o[0] = f2bf(a.x); o[1] = f2bf(a.y); o[2] = f2bf(a.z); o[3] = f2bf(a.w);
  o[4] = f2bf(b.x); o[5] = f2bf(b.y); o[6] = f2bf(b.z); o[7] = f2bf(b.w);
  *((ushort8v*)out + i) = o;
}

// ---------------- deep-phase GEMM: C[M][N] = A[M][K] * B[N][K]^T ----------
// BN=256 fixed, BK=64, K=2048 (NT=32), 8 waves (2M x 4N), 512 threads.
// BM=256: 4 phases/K-tile; BM=128: 2 phases/K-tile.
// Double-buffered LDS, XOR-swizzled (st-style), counted vmcnt: next tile's
// global_load_lds stay in flight across raw s_barrier phases; single
// vmcnt(0) per K-tile at iter top.
template<int BM>
__global__ __launch_bounds__(512, 2) void gemm8p(const unsigned short* __restrict__ A,
                                                 const unsigned short* __restrict__ B,
                                                 float* __restrict__ C,
                                                 int N) {
  constexpr int ABYTES = BM * 128;          // A tile bytes (BM rows x 64 cols bf16)
  constexpr int ACH = ABYTES / 8192;        // A stage chunks (4 or 2)
  constexpr int SCH = ACH + 4;              // total stage chunks per K-tile
  constexpr int MFR = BM / 32;              // A frags per wave (8 or 4)
  __shared__ char lds[2 * ABYTES + 2 * 32768];

  const char* Ag = (const char*)A;
  const char* Bg = (const char*)B;

  // chunked XCD swizzle (nwg % 8 == 0 guaranteed: 192 / 128)
  int nwg = gridDim.x;
  int cpx = nwg >> 3;
  int orig = blockIdx.x;
  int swz = (orig & 7) * cpx + (orig >> 3);
  int nbx = N >> 8;
  int bx = swz % nbx, by = swz / nbx;
  int tileM = by * BM, tileN = bx * 256;

  int tid = threadIdx.x;
  int w = tid >> 6, lane = tid & 63;
  int l15 = lane & 15, l4 = lane >> 4;
  int wm = w >> 2, wn = w & 3;
  int xorsw = (l15 & 7) << 4;

  f32x4 acc[MFR][4] = {};
  bf16x8 a[4][2], b0[2][2], b1[2][2];

  auto stage = [&](int i, int kt, int bsel) {
    char* dst;
    const char* src;
    if (i < ACH) {
      int L = (i * 512 + tid) * 16;
      int row = L >> 7, colb = L & 127;
      dst = lds + bsel * ABYTES + L;
      src = Ag + (size_t)(tileM + row) * 4096 + kt * 128 + (colb ^ ((row & 7) << 4));
    } else {
      int L = ((i - ACH) * 512 + tid) * 16;
      int row = L >> 7, colb = L & 127;
      dst = lds + 2 * ABYTES + bsel * 32768 + L;
      src = Bg + (size_t)(tileN + row) * 4096 + kt * 128 + (colb ^ ((row & 7) << 4));
    }
    __builtin_amdgcn_global_load_lds((gas_cvp)src, (las_vp)dst, 16, 0, 0);
  };
  auto readA = [&](int ah, const char* Ab) {
    #pragma unroll
    for (int mfl = 0; mfl < 4; ++mfl)
      #pragma unroll
      for (int kk = 0; kk < 2; ++kk) {
        int row = wm * (BM / 2) + (ah * 4 + mfl) * 16 + l15;
        a[mfl][kk] = *(const bf16x8*)(Ab + row * 128 + ((kk * 64 + l4 * 16) ^ xorsw));
      }
  };
  auto readB = [&](bf16x8 (&bb)[2][2], int bh, const char* Bb) {
    #pragma unroll
    for (int nfl = 0; nfl < 2; ++nfl)
      #pragma unroll
      for (int kk = 0; kk < 2; ++kk) {
        int row = wn * 64 + (bh * 2 + nfl) * 16 + l15;
        bb[nfl][kk] = *(const bf16x8*)(Bb + row * 128 + ((kk * 64 + l4 * 16) ^ xorsw));
      }
  };
  auto mfma16 = [&](int ah, int bh, bf16x8 (&bb)[2][2]) {
    __builtin_amdgcn_s_setprio(1);
    #pragma unroll
    for (int mfl = 0; mfl < 4; ++mfl)
      #pragma unroll
      for (int nfl = 0; nfl < 2; ++nfl)
        #pragma unroll
        for (int kk = 0; kk < 2; ++kk)
          acc[ah * 4 + mfl][bh * 2 + nfl] =
            __builtin_amdgcn_mfma_f32_16x16x32_bf16(a[mfl][kk], bb[nfl][kk],
                                                    acc[ah * 4 + mfl][bh * 2 + nfl], 0, 0, 0);
    __builtin_amdgcn_s_setprio(0);
  };

  // prologue: stage K-tile 0 into buffer 0
  #pragma unroll
  for (int i = 0; i < SCH; ++i) stage(i, 0, 0);

  #pragma unroll 2
  for (int t = 0; t < 32; ++t) {
    int buf = t & 1;
    const char* Ab = lds + buf * ABYTES;
    const char* Bb = lds + 2 * ABYTES + buf * 32768;
    bool pf = (t + 1 < 32);

    // iter-top sync: my loads done, then all waves' loads done; fence reads.
    asm volatile("s_waitcnt vmcnt(0)" ::: "memory");
    __builtin_amdgcn_s_barrier();
    asm volatile("" ::: "memory");

    if constexpr (BM == 256) {
      // p0: (a0,b0)
      readA(0, Ab); readB(b0, 0, Bb);
      if (pf) { stage(0, t + 1, buf ^ 1); stage(1, t + 1, buf ^ 1);
                stage(2, t + 1, buf ^ 1); stage(3, t + 1, buf ^ 1); }
      __builtin_amdgcn_s_barrier();
      mfma16(0, 0, b0);
      __builtin_amdgcn_s_barrier();
      // p1: (a0,b1)
      readB(b1, 1, Bb);
      if (pf) { stage(4, t + 1, buf ^ 1); stage(5, t + 1, buf ^ 1);
                stage(6, t + 1, buf ^ 1); stage(7, t + 1, buf ^ 1); }
      __builtin_amdgcn_s_barrier();
      mfma16(0, 1, b1);
      __builtin_amdgcn_s_barrier();
      // p2: (a1,b1)
      readA(1, Ab);
      __builtin_amdgcn_s_barrier();
      mfma16(1, 1, b1);
      __builtin_amdgcn_s_barrier();
      // p3: (a1,b0)
      mfma16(1, 0, b0);
      __builtin_amdgcn_s_barrier();
    } else {
      // p0: (a0,b0), stage all 6 chunks
      readA(0, Ab); readB(b0, 0, Bb);
      if (pf) { stage(0, t + 1, buf ^ 1); stage(1, t + 1, buf ^ 1);
                stage(2, t + 1, buf ^ 1); stage(3, t + 1, buf ^ 1);
                stage(4, t + 1, buf ^ 1); stage(5, t + 1, buf ^ 1); }
      __builtin_amdgcn_s_barrier();
      mfma16(0, 0, b0);
      __builtin_amdgcn_s_barrier();
      // p1: (a0,b1)
      readB(b1, 1, Bb);
      __builtin_amdgcn_s_barrier();
      mfma16(0, 1, b1);
      __builtin_amdgcn_s_barrier();
    }
  }

  // epilogue: fp32 C write
  #pragma unroll
  for (int mf = 0; mf < MFR; ++mf) {
    int r0 = tileM + wm * (BM / 2) + mf * 16 + l4 * 4;
    #pragma unroll
    for (int nf = 0; nf < 4; ++nf) {
      int c0 = tileN + wn * 64 + nf * 16 + l15;
      #pragma unroll
      for (int j = 0; j < 4; ++j)
        C[(size_t)(r0 + j) * N + c0] = acc[mf][nf][j];
    }
  }
}

// ---------------- v-mix + RMSNorm + RoPE (one wave per (t,h)) -------------
__global__ __launch_bounds__(256) void qkv_post(const float* __restrict__ qkv,
                                                const float* __restrict__ vi,
                                                const float* __restrict__ lam,
                                                unsigned short* __restrict__ qb,
                                                unsigned short* __restrict__ kb,
                                                unsigned short* __restrict__ vb) {
  int wid = blockIdx.x * 4 + (threadIdx.x >> 6);
  int lane = threadIdx.x & 63;
  int t = wid >> 4, h = wid & 15;
  const float* base = qkv + (size_t)t * (3 * DM) + h * 128;
  float l0 = lam[0], l1 = lam[1];

  float invf = exp2f((float)lane * -0.20762050593046014f);
  float ang = (float)t * invf;
  float sn, cs;
  sincosf(ang, &sn, &cs);

  size_t ob = (size_t)t * DM + h * 128;
  {
    float a = base[lane], b = base[lane + 64];
    float ss = a * a + b * b;
    #pragma unroll
    for (int m = 1; m < 64; m <<= 1) ss += __shfl_xor(ss, m, 64);
    float sc = rsqrtf(ss * (1.0f / 128.0f) + 1.1920929e-07f);
    a *= sc; b *= sc;
    qb[ob + lane]      = f2bf(a * cs + b * sn);
    qb[ob + 64 + lane] = f2bf(b * cs - a * sn);
  }
  {
    float a = base[2048 + lane], b = base[2048 + 64 + lane];
    float ss = a * a + b * b;
    #pragma unroll
    for (int m = 1; m < 64; m <<= 1) ss += __shfl_xor(ss, m, 64);
    float sc = rsqrtf(ss * (1.0f / 128.0f) + 1.1920929e-07f);
    a *= sc; b *= sc;
    kb[ob + lane]      = f2bf(a * cs + b * sn);
    kb[ob + 64 + lane] = f2bf(b * cs - a * sn);
  }
  {
    const float* vib = vi + (size_t)t * DM + h * 128;
    vb[ob + lane]      = f2bf(l0 * base[4096 + lane]      + l1 * vib[lane]);
    vb[ob + 64 + lane] = f2bf(l0 * base[4096 + 64 + lane] + l1 * vib[lane + 64]);
  }
}

// ---------------- V transpose: vb[t][h*128+d] -> vbT[h][d][t] -------------
__global__ __launch_bounds__(256) void transpose_v(const unsigned short* __restrict__ vb,
                                                   unsigned short* __restrict__ vbT) {
  __shared__ __align__(16) unsigned short tile[64][68];
  int t0 = blockIdx.x * 64, d0 = blockIdx.y * 64, h = blockIdx.z;
  int tid = threadIdx.x;
  int li = tid >> 4;
  int lj = (tid & 15) * 4;
  #pragma unroll
  for (int p = 0; p < 4; ++p) {
    int i = p * 16 + li;
    ushort4 v = *(const ushort4*)(vb + (size_t)(t0 + i) * DM + h * 128 + d0 + lj);
    tile[i][lj] = v.x; tile[i][lj + 1] = v.y; tile[i][lj + 2] = v.z; tile[i][lj + 3] = v.w;
  }
  __syncthreads();
  #pragma unroll
  for (int p = 0; p < 4; ++p) {
    int j = p * 16 + li;
    ushort4 wv;
    wv.x = tile[lj][j]; wv.y = tile[lj + 1][j]; wv.z = tile[lj + 2][j]; wv.w = tile[lj + 3][j];
    *(ushort4*)(vbT + (size_t)h * 128 * TSEQ + (size_t)(d0 + j) * TSEQ + t0 + lj) = wv;
  }
}

// ---------------- causal flash attention -----------------------------------
__global__ __launch_bounds__(256) void attn_fwd(const unsigned short* __restrict__ qb,
                                                const unsigned short* __restrict__ kb,
                                                const unsigned short* __restrict__ vbT,
                                                unsigned short* __restrict__ yb) {
  __shared__ __align__(16) char Ks[2][16384];
  __shared__ __align__(16) char Vs[2][16384];
  __shared__ __align__(16) unsigned short p_lds[4][16][80];

  int qblk = (int)gridDim.x - 1 - (int)blockIdx.x;
  int h = blockIdx.y;
  int tid = threadIdx.x, w = tid >> 6, lane = tid & 63;
  int l15 = lane & 15, l4 = lane >> 4;
  int qr0 = qblk * 64 + w * 16;
  int xorK = (l15 & 7) << 4;

  const unsigned short* qrow = qb + (size_t)(qr0 + l15) * DM + h * 128 + l4 * 8;
  bf16x8 a_q[4];
  #pragma unroll
  for (int kk = 0; kk < 4; ++kk) a_q[kk] = *(const bf16x8*)(qrow + kk * 32);

  const char* kbase = (const char*)kb + (size_t)h * 256;
  const char* vbase = (const char*)vbT + (size_t)h * 128 * TSEQ * 2;

  f32x4 acc_o[8] = {};
  float mrow[4] = {-1e30f, -1e30f, -1e30f, -1e30f};
  float lrow[4] = {0.f, 0.f, 0.f, 0.f};
  const float scale = 0.08838834764831845f;

  int nkv = qblk + 1;

  {
    #pragma unroll
    for (int it = 0; it < 4; ++it) {
      int L = (it * 256 + tid) * 16;
      int row = L >> 8, b = L & 255;
      const char* src = kbase + (size_t)row * 4096 + (b ^ ((row & 7) << 4));
      __builtin_amdgcn_global_load_lds((gas_cvp)src, (las_vp)(&Ks[0][0] + L), 16, 0, 0);
    }
    #pragma unroll
    for (int it = 0; it < 4; ++it) {
      int L = (it * 256 + tid) * 16;
      int row = L >> 7, b = L & 127;
      const char* src = vbase + (size_t)row * (TSEQ * 2) + (b ^ ((row & 7) << 4));
      __builtin_amdgcn_global_load_lds((gas_cvp)src, (las_vp)(&Vs[0][0] + L), 16, 0, 0);
    }
  }
  __syncthreads();

  int buf = 0;
  for (int kvb = 0; kvb < nkv; ++kvb) {
    int kv0 = kvb * 64;
    if (kvb + 1 < nkv) {
      int kv1 = (kvb + 1) * 64;
      const char* kb1 = kbase + (size_t)kv1 * 4096;
      const char* vb1 = vbase + (size_t)kv1 * 2;
      char* kd = &Ks[buf ^ 1][0];
      char* vd = &Vs[buf ^ 1][0];
      #pragma unroll
      for (int it = 0; it < 4; ++it) {
        int L = (it * 256 + tid) * 16;
        int row = L >> 8, b = L & 255;
        const char* src = kb1 + (size_t)row * 4096 + (b ^ ((row & 7) << 4));
        __builtin_amdgcn_global_load_lds((gas_cvp)src, (las_vp)(kd + L), 16, 0, 0);
      }
      #pragma unroll
      for (int it = 0; it < 4; ++it) {
        int L = (it * 256 + tid) * 16;
        int row = L >> 7, b = L & 127;
        const char* src = vb1 + (size_t)row * (TSEQ * 2) + (b ^ ((row & 7) << 4));
        __builtin_amdgcn_global_load_lds((gas_cvp)src, (las_vp)(vd + L), 16, 0, 0);
      }
    }

    const char* ksb = &Ks[buf][0];
    const char* vsb = &Vs[buf][0];

    f32x4 acc_s[4] = {};
    __builtin_amdgcn_s_setprio(1);
    #pragma unroll
    for (int j = 0; j < 4; ++j) {
      const char* kr = ksb + (j * 16 + l15) * 256;
      #pragma unroll
      for (int kk = 0; kk < 4; ++kk) {
        bf16x8 bk = *(const bf16x8*)(kr + ((l4 * 16 + kk * 64) ^ xorK));
        acc_s[j] = __builtin_amdgcn_mfma_f32_16x16x32_bf16(a_q[kk], bk, acc_s[j], 0, 0, 0);
      }
    }
    __builtin_amdgcn_s_setprio(0);

    bool diag = (kvb == qblk);
    float sv[4][4];
    float pmax[4] = {-1e30f, -1e30f, -1e30f, -1e30f};
    #pragma unroll
    for (int j = 0; j < 4; ++j)
      #pragma unroll
      for (int r = 0; r < 4; ++r) {
        float s = acc_s[j][r] * scale;
        if (diag && (kv0 + j * 16 + l15) > (qr0 + l4 * 4 + r)) s = -1e30f;
        sv[j][r] = s;
        pmax[r] = fmaxf(pmax[r], s);
      }
    #pragma unroll
    for (int m = 1; m < 16; m <<= 1)
      #pragma unroll
      for (int r = 0; r < 4; ++r) pmax[r] = fmaxf(pmax[r], __shfl_xor(pmax[r], m, 64));
    float f[4], psum[4] = {0, 0, 0, 0};
    #pragma unroll
    for (int r = 0; r < 4; ++r) {
      float mn = fmaxf(mrow[r], pmax[r]);
      f[r] = __expf(mrow[r] - mn);
      mrow[r] = mn;
    }
    #pragma unroll
    for (int j = 0; j < 4; ++j)
      #pragma unroll
      for (int r = 0; r < 4; ++r) {
        float p = __expf(sv[j][r] - mrow[r]);
        psum[r] += p;
        p_lds[w][l4 * 4 + r][j * 16 + l15] = f2bf(p);
      }
    #pragma unroll
    for (int m = 1; m < 16; m <<= 1)
      #pragma unroll
      for (int r = 0; r < 4; ++r) psum[r] += __shfl_xor(psum[r], m, 64);
    #pragma unroll
    for (int r = 0; r < 4; ++r) lrow[r] = lrow[r] * f[r] + psum[r];
    #pragma unroll
    for (int n = 0; n < 8; ++n)
      #pragma unroll
      for (int r = 0; r < 4; ++r) acc_o[n][r] *= f[r];
    asm volatile("s_waitcnt lgkmcnt(0)" ::: "memory");
    __builtin_amdgcn_sched_barrier(0);

    __builtin_amdgcn_s_setprio(1);
    #pragma unroll
    for (int kk = 0; kk < 2; ++kk) {
      bf16x8 a_p = *(const bf16x8*)&p_lds[w][l15][kk * 32 + l4 * 8];
      #pragma unroll
      for (int n = 0; n < 8; ++n) {
        const char* vr = vsb + (n * 16 + l15) * 128;
        bf16x8 bv = *(const bf16x8*)(vr + ((kk * 64 + l4 * 16) ^ xorK));
        acc_o[n] = __builtin_amdgcn_mfma_f32_16x16x32_bf16(a_p, bv, acc_o[n], 0, 0, 0);
      }
    }
    __builtin_amdgcn_s_setprio(0);

    __syncthreads();
    buf ^= 1;
  }

  #pragma unroll
  for (int n = 0; n < 8; ++n)
    #pragma unroll
    for (int r = 0; r < 4; ++r) {
      float o = acc_o[n][r] / lrow[r];
      yb[(size_t)(qr0 + l4 * 4 + r) * DM + h * 128 + n * 16 + l15] = f2bf(o);
    }
}

// ---------------------------------------------------------------------------
extern "C" void kernel_launch(void* const* d_in, const int* in_sizes, int n_in,
                              void* d_out, int out_size, void* d_ws, size_t ws_size,
                              hipStream_t stream) {
  const float* x   = (const float*)d_in[0];
  const float* vi  = (const float*)d_in[1];
  const float* wq  = (const float*)d_in[2];
  const float* wk  = (const float*)d_in[3];
  const float* wv  = (const float*)d_in[4];
  const float* wp  = (const float*)d_in[5];
  const float* lam = (const float*)d_in[6];

  const size_t MB = 1024 * 1024;
  const int NEL = DM * TSEQ;
  const int N8  = NEL / 8;
  char* ws = (char*)d_ws;
  unsigned short* xb    = (unsigned short*)(ws);
  unsigned short* wqkvb = (unsigned short*)(ws + 8  * MB);
  unsigned short* wpb   = (unsigned short*)(ws + 32 * MB);
  float*          qkv32 = (float*)(ws + 40 * MB);
  unsigned short* qb2   = (unsigned short*)(ws + 88 * MB);
  unsigned short* kb2   = (unsigned short*)(ws + 96 * MB);
  unsigned short* vb    = (unsigned short*)(ws + 104 * MB);
  unsigned short* vbT   = (unsigned short*)(ws + 112 * MB);
  unsigned short* yb    = (unsigned short*)(ws + 120 * MB);

  cvt_bf16<<<N8 / 256, 256, 0, stream>>>(x,  xb, N8);
  cvt_bf16<<<N8 / 256, 256, 0, stream>>>(wq, wqkvb,                  N8);
  cvt_bf16<<<N8 / 256, 256, 0, stream>>>(wk, wqkvb + (size_t)NEL,     N8);
  cvt_bf16<<<N8 / 256, 256, 0, stream>>>(wv, wqkvb + (size_t)2 * NEL, N8);
  cvt_bf16<<<N8 / 256, 256, 0, stream>>>(wp, wpb, N8);

  // QKV: [2048,2048] x [6144,2048]^T, grid 24x8=192 (one pass, 1 block/CU)
  gemm8p<256><<<192, 512, 0, stream>>>(xb, wqkvb, qkv32, 3 * DM);

  qkv_post<<<(TSEQ * NHEAD) / 4, 256, 0, stream>>>(qkv32, vi, lam, qb2, kb2, vb);

  transpose_v<<<dim3(TSEQ / 64, 2, NHEAD), 256, 0, stream>>>(vb, vbT);

  attn_fwd<<<dim3(TSEQ / 64, NHEAD), 256, 0, stream>>>(qb2, kb2, vbT, yb);

  // proj: [2048,2048] x [2048,2048]^T, BM=128 -> grid 8x16=128 (one pass)
  gemm8p<128><<<128, 512, 0, stream>>>(yb, wpb, (float*)d_out, DM);
}